// Round 8
// baseline (101.061 us; speedup 1.0000x reference)
//
#include <hip/hip_runtime.h>
#include <hip/hip_bf16.h>
#include <math.h>

#define BB    256   // batch
#define LL    256   // seq len
#define NV    14    // vocab
#define EMBD  512
#define H2    128   // L//2
#define OC    256   // branch conv out channels
#define NP    196   // 14*14 ordered token pairs
#define JD    128   // branch linear out
#define MO    64    // manip conv out channels
#define MJ    256   // manip linear out

// prep block ranges
#define PB_PAIRS  392
#define PB_CWT    256                   // 2 br * 4 o-chunks * 32 i-chunks
#define PB_MANIPW 96
#define PB_LINT   64
#define PB_LWT    1024                  // 2 br * 128 h * 4 o-blocks

using s16x8 = __attribute__((ext_vector_type(8))) short;
using f32x4 = __attribute__((ext_vector_type(4))) float;

static __device__ __forceinline__ unsigned short f2bf_rne(float f) {
    unsigned int u = __float_as_uint(f);
    unsigned int r = (u + 0x7FFFu + ((u >> 16) & 1u)) >> 16;
    return (unsigned short)r;
}
static __device__ __forceinline__ float bf2f(unsigned short h) {
    return __uint_as_float(((unsigned int)h) << 16);
}

// ---------- combined prep: pairs | cwt | manipw | lint | lwT transpose ----------
__global__ void k_prep(const float* __restrict__ emb_e, const float* __restrict__ emb_f,
                       const float* __restrict__ cw_e, const float* __restrict__ cw_f,
                       const float* __restrict__ mcw, const float* __restrict__ mlw,
                       const float* __restrict__ elw, const float* __restrict__ flw1,
                       float* __restrict__ P, float* __restrict__ cwT,
                       float* __restrict__ Wc, float* __restrict__ Lint,
                       unsigned short* __restrict__ lwT_hi, unsigned short* __restrict__ lwT_lo) {
    __shared__ float T[48][66];          // cwt transpose tile (also aliased below)
    __shared__ unsigned short Th[64][132];
    __shared__ unsigned short Tl[64][132];
    int bid = blockIdx.x;
    int t = threadIdx.x;
    if (bid < PB_PAIRS) {                  // pairs: P[br][q][c]
        int q = bid % NP, br = bid / NP;
        const float* emb = br ? emb_f : emb_e;
        int t1 = q / NV, t2 = q % NV;
        float* outp = P + ((size_t)br * NP + q) * EMBD;
        for (int c = t; c < EMBD; c += 256)
            outp[c] = fmaxf(emb[t1 * EMBD + c], emb[t2 * EMBD + c]);
    } else if (bid < PB_PAIRS + PB_CWT) {  // cwt: coalesced read + LDS transpose
        int cb = bid - PB_PAIRS;           // 0..255
        int ic = cb & 31;                  // i-chunk (16 i's)
        int oc = (cb >> 5) & 3;            // o-chunk (64 o's)
        int br = cb >> 7;                  // branch
        int i0 = ic * 16, o0 = oc * 64;
        const float* cw = br ? cw_f : cw_e;
        int ol = t >> 2, part = t & 3;     // o_local 0..63, i-quarter 0..3
        const float* src = cw + ((size_t)(o0 + ol) * EMBD + i0) * 9 + part * 36;
        #pragma unroll
        for (int ii = 0; ii < 4; ++ii)
            #pragma unroll
            for (int kh = 0; kh < 3; ++kh)
                T[kh * 16 + part * 4 + ii][ol] = src[ii * 9 + kh * 3 + 1];
        __syncthreads();
        int lane = t & 63, r0 = t >> 6;
        for (int rr = r0; rr < 48; rr += 4) {
            int kh = rr >> 4, il = rr & 15;
            cwT[(((size_t)(br * 3 + kh)) * EMBD + i0 + il) * OC + o0 + lane] = T[rr][lane];
        }
    } else if (bid < PB_PAIRS + PB_CWT + PB_MANIPW) {  // manipw
        int idx = (bid - PB_PAIRS - PB_CWT) * 256 + t;
        int o = idx & 63;
        int i = (idx >> 6) & 127;
        int cls = idx >> 13;
        const float* base = mcw + ((size_t)(o * 128 + i) * 3) * 3 + 1;
        float v = 0.f;
        if (cls != 2) { v += base[3]; v += base[6]; }
        else          { v += base[0]; v += base[3]; }
        if (cls == 1)   v += base[0];
        Wc[idx] = v;
    } else if (bid < PB_PAIRS + PB_CWT + PB_MANIPW + PB_LINT) {  // lint
        int o = bid - (PB_PAIRS + PB_CWT + PB_MANIPW);   // 0..63
        float s = 0.f;
        for (int h = 1; h <= 126; h++)
            s += mlw[((size_t)(o * H2 + h)) * MJ + t];
        Lint[o * 256 + t] = s;
    } else {                                // lwT transpose: bf16 hi(/lo) [br][h][j][o]
        int lb = bid - (PB_PAIRS + PB_CWT + PB_MANIPW + PB_LINT);  // 0..1023
        int br = lb >> 9;                  // 0 enemy, 1 friend
        int rem = lb & 511;
        int h = rem >> 2;
        int ob = rem & 3;
        int o0 = ob * 64;
        const float* src = br ? flw1 : elw;
        int o_l = t >> 2, jq = t & 3;
        const float* srow = src + ((size_t)(o0 + o_l) * H2 + h) * JD + jq * 32;
        #pragma unroll
        for (int p = 0; p < 8; ++p) {
            float4 v = *(const float4*)(srow + p * 4);
            int j = jq * 32 + p * 4;
            unsigned short h0 = f2bf_rne(v.x), h1 = f2bf_rne(v.y);
            unsigned short h2 = f2bf_rne(v.z), h3 = f2bf_rne(v.w);
            uint2 u;
            u.x = (unsigned)h0 | ((unsigned)h1 << 16);
            u.y = (unsigned)h2 | ((unsigned)h3 << 16);
            *(uint2*)&Th[o_l][j] = u;
            if (br == 0) {
                unsigned short l0 = f2bf_rne(v.x - bf2f(h0));
                unsigned short l1 = f2bf_rne(v.y - bf2f(h1));
                unsigned short l2 = f2bf_rne(v.z - bf2f(h2));
                unsigned short l3 = f2bf_rne(v.w - bf2f(h3));
                uint2 w;
                w.x = (unsigned)l0 | ((unsigned)l1 << 16);
                w.y = (unsigned)l2 | ((unsigned)l3 << 16);
                *(uint2*)&Tl[o_l][j] = w;
            }
        }
        __syncthreads();
        int j = t >> 1, half = t & 1;
        union { unsigned short u16[32]; uint4 u4[4]; } pk;
        #pragma unroll
        for (int oo = 0; oo < 32; ++oo) pk.u16[oo] = Th[half * 32 + oo][j];
        unsigned short* dst = lwT_hi + (((size_t)br * H2 + h) * 128 + j) * 256 + o0 + half * 32;
        #pragma unroll
        for (int kk = 0; kk < 4; ++kk) *(uint4*)(dst + kk * 8) = pk.u4[kk];
        if (br == 0) {
            #pragma unroll
            for (int oo = 0; oo < 32; ++oo) pk.u16[oo] = Tl[half * 32 + oo][j];
            unsigned short* dstl = lwT_lo + (((size_t)h) * 128 + j) * 256 + o0 + half * 32;
            #pragma unroll
            for (int kk = 0; kk < 4; ++kk) *(uint4*)(dstl + kk * 8) = pk.u4[kk];
        }
    }
}

// ---------- pair contributions, full K, q-batch 4: C[(br*NP+q)*3+kh][o] ----------
__global__ __launch_bounds__(256) void k_contrib(
        const float* __restrict__ P, const float* __restrict__ cwT,
        const float* __restrict__ cb_e, const float* __restrict__ cb_f,
        float* __restrict__ C) {
    int bid = blockIdx.x;               // (br*3+kh)*49+qg
    int qg = bid % 49;
    int kh = (bid / 49) % 3;
    int br = bid / 147;
    int o = threadIdx.x;

    __shared__ float Pl[4][512];
    for (int idx = o; idx < 4 * 512; idx += 256) {
        int row = idx >> 9, col = idx & 511;
        Pl[row][col] = P[((size_t)br * NP + qg * 4 + row) * EMBD + col];
    }
    __syncthreads();

    const float* w = cwT + ((size_t)(br * 3 + kh) * EMBD) * OC + o;
    float acc[4] = {0.f, 0.f, 0.f, 0.f};
    #pragma unroll 8
    for (int i = 0; i < 512; i++) {
        float wv = w[(size_t)i * OC];
        #pragma unroll
        for (int qq = 0; qq < 4; qq++) acc[qq] = fmaf(wv, Pl[qq][i], acc[qq]);
    }
    float cbv = (kh == 1) ? (br ? cb_f[o] : cb_e[o]) : 0.f;
    #pragma unroll
    for (int qq = 0; qq < 4; qq++)
        C[(((size_t)br * NP + qg * 4 + qq) * 3 + kh) * OC + o] = acc[qq] + cbv;
}

// ---------- MFMA GEMM: partial[b][h][j] = sum_o Y[b,h,o]*lw[(o*H2+h)*JD+j] ----------
// B operand comes pre-transposed/pre-split as bf16 lwT[h][j][o] — staging is
// pure vector copy. M-tile 64, grid (H2,4)=512 blocks, 2 blocks/CU, 8 waves.
template <int X3>
__global__ __launch_bounds__(512) void k_gemm(
        const int* __restrict__ tok, const float* __restrict__ C,
        const unsigned short* __restrict__ lwTh, const unsigned short* __restrict__ lwTl,
        float* __restrict__ partial) {
    __shared__ unsigned short Ah[2][64][36];
    __shared__ unsigned short Al[2][64][36];
    __shared__ unsigned short Bh[2][128][36];
    __shared__ unsigned short Bl[2][128][36];

    const int h  = blockIdx.x;
    const int B0 = blockIdx.y * 64;
    const int t  = threadIdx.x;

    // ---- A gather setup (thread: row am 0..63, k-quad kq of 4 floats)
    const int am = t >> 3;
    const int kq = (t & 7) * 4;
    const int* tb = tok + (size_t)(B0 + am) * LL;
    const int q1 = tb[2 * h] * NV + tb[2 * h + 1];
    const float* r1 = C + ((size_t)q1 * 3 + 1) * OC + kq;
    const float* r0 = nullptr;
    const float* r2 = nullptr;
    if (h > 0)      { int q0 = tb[2 * h - 2] * NV + tb[2 * h - 1]; r0 = C + ((size_t)q0 * 3 + 0) * OC + kq; }
    if (h < H2 - 1) { int q2 = tb[2 * h + 2] * NV + tb[2 * h + 3]; r2 = C + ((size_t)q2 * 3 + 2) * OC + kq; }

    // ---- B setup (thread: j-row jb 0..127, 8 k's at kq8)
    const int jb = t >> 2;
    const int kq8 = (t & 3) * 8;
    const unsigned short* wTh = lwTh + ((size_t)h * 128 + jb) * 256 + kq8;
    const unsigned short* wTl = X3 ? (lwTl + ((size_t)h * 128 + jb) * 256 + kq8) : nullptr;

    float4 ya, yb, yc;
    uint4 wh4, wl4;

    auto load = [&](int s) {
        ya = *(const float4*)(r1 + s * 32);
        if (r0) yb = *(const float4*)(r0 + s * 32);
        else    yb = make_float4(0, 0, 0, 0);
        if (r2) yc = *(const float4*)(r2 + s * 32);
        else    yc = make_float4(0, 0, 0, 0);
        wh4 = *(const uint4*)(wTh + (size_t)s * 32);
        if (X3) wl4 = *(const uint4*)(wTl + (size_t)s * 32);
    };

    auto store = [&](int buf) {
        float y[4];
        y[0] = ya.x + yb.x + yc.x; y[1] = ya.y + yb.y + yc.y;
        y[2] = ya.z + yb.z + yc.z; y[3] = ya.w + yb.w + yc.w;
        unsigned short hi[4];
        #pragma unroll
        for (int e = 0; e < 4; ++e) hi[e] = f2bf_rne(y[e]);
        uint2 u;
        u.x = (unsigned)hi[0] | ((unsigned)hi[1] << 16);
        u.y = (unsigned)hi[2] | ((unsigned)hi[3] << 16);
        *(uint2*)&Ah[buf][am][kq] = u;
        if (X3) {
            uint2 v;
            unsigned short lo[4];
            #pragma unroll
            for (int e = 0; e < 4; ++e) lo[e] = f2bf_rne(y[e] - bf2f(hi[e]));
            v.x = (unsigned)lo[0] | ((unsigned)lo[1] << 16);
            v.y = (unsigned)lo[2] | ((unsigned)lo[3] << 16);
            *(uint2*)&Al[buf][am][kq] = v;
        }
        *(uint2*)&Bh[buf][jb][kq8]     = make_uint2(wh4.x, wh4.y);
        *(uint2*)&Bh[buf][jb][kq8 + 4] = make_uint2(wh4.z, wh4.w);
        if (X3) {
            *(uint2*)&Bl[buf][jb][kq8]     = make_uint2(wl4.x, wl4.y);
            *(uint2*)&Bl[buf][jb][kq8 + 4] = make_uint2(wl4.z, wl4.w);
        }
    };

    // ---- compute mapping: 8 waves = 2m x 4n; wave tile 32m x 32n
    const int lane = t & 63, wid = t >> 6;
    const int Wm = (wid >> 2) * 32;     // 0 or 32
    const int Wn = (wid & 3) * 32;      // 0,32,64,96
    const int fr = lane & 15;
    const int g8 = (lane >> 4) * 8;

    f32x4 acc[2][2] = {};

    auto rd8 = [&](const unsigned short* p) -> s16x8 {
        union { s16x8 v; uint2 u[2]; } tmp;
        tmp.u[0] = *(const uint2*)(p);
        tmp.u[1] = *(const uint2*)(p + 4);
        return tmp.v;
    };

    auto compute = [&](int buf) {
        s16x8 a_h[2], b_h[2];
        #pragma unroll
        for (int mf = 0; mf < 2; ++mf) a_h[mf] = rd8(&Ah[buf][Wm + mf * 16 + fr][g8]);
        #pragma unroll
        for (int nf = 0; nf < 2; ++nf) b_h[nf] = rd8(&Bh[buf][Wn + nf * 16 + fr][g8]);
        #pragma unroll
        for (int mf = 0; mf < 2; ++mf)
            #pragma unroll
            for (int nf = 0; nf < 2; ++nf)
                acc[mf][nf] = __builtin_amdgcn_mfma_f32_16x16x32_bf16(a_h[mf], b_h[nf], acc[mf][nf], 0, 0, 0);
        if (X3) {
            s16x8 a_l[2], b_l[2];
            #pragma unroll
            for (int mf = 0; mf < 2; ++mf) a_l[mf] = rd8(&Al[buf][Wm + mf * 16 + fr][g8]);
            #pragma unroll
            for (int nf = 0; nf < 2; ++nf) b_l[nf] = rd8(&Bl[buf][Wn + nf * 16 + fr][g8]);
            #pragma unroll
            for (int mf = 0; mf < 2; ++mf)
                #pragma unroll
                for (int nf = 0; nf < 2; ++nf) {
                    acc[mf][nf] = __builtin_amdgcn_mfma_f32_16x16x32_bf16(a_h[mf], b_l[nf], acc[mf][nf], 0, 0, 0);
                    acc[mf][nf] = __builtin_amdgcn_mfma_f32_16x16x32_bf16(a_l[mf], b_h[nf], acc[mf][nf], 0, 0, 0);
                }
        }
    };

    // ---- main loop
    load(0);
    store(0);
    __syncthreads();
    for (int s = 0; s < 8; ++s) {
        if (s < 7) load(s + 1);
        compute(s & 1);
        if (s < 7) store((s + 1) & 1);
        __syncthreads();
    }

    // ---- epilogue: partial[b][h][j]; D mapping col=lane&15, row=4*(lane>>4)+reg
    float* pb = partial + (((size_t)(B0 + Wm)) * H2 + h) * JD + Wn;
    #pragma unroll
    for (int mf = 0; mf < 2; ++mf)
        #pragma unroll
        for (int nf = 0; nf < 2; ++nf)
            #pragma unroll
            for (int r = 0; r < 4; ++r) {
                int row = mf * 16 + (lane >> 4) * 4 + r;
                int col = nf * 16 + fr;
                pb[(size_t)row * H2 * JD + col] = acc[mf][nf][r];
            }
}

// ---------- fuse E: reduce + softmax + manip conv + manip linear + tokens ----------
__global__ __launch_bounds__(256) void k_fuseE(
        const float* __restrict__ partial, const float* __restrict__ elb,
        const float* __restrict__ Wc, const float* __restrict__ mcb,
        const float* __restrict__ mlw, const float* __restrict__ Lint,
        const float* __restrict__ mlb, int* __restrict__ tokens) {
    int b = blockIdx.x, t = threadIdx.x;
    __shared__ float S[2][128];
    __shared__ float eo[128];
    __shared__ float m3[3][64];
    __shared__ float red[128];

    int j = t & 127, hh = t >> 7;
    float s = 0.f;
    const float* pbase = partial + (size_t)b * H2 * JD + j;
    for (int h = hh * 64; h < hh * 64 + 64; ++h)
        s += pbase[(size_t)h * JD];
    S[hh][j] = s;
    __syncthreads();
    if (t < 128) {
        float v = S[0][t] + S[1][t] + elb[t];
        S[0][t] = v;
        red[t] = v;
    }
    __syncthreads();
    for (int st = 64; st > 0; st >>= 1) {
        if (t < st) red[t] = fmaxf(red[t], red[t + st]);
        __syncthreads();
    }
    float mx = red[0];
    __syncthreads();
    if (t < 128) {
        float e = expf(S[0][t] - mx);
        eo[t] = e;
        red[t] = e;
    }
    __syncthreads();
    for (int st = 64; st > 0; st >>= 1) {
        if (t < st) red[t] += red[t + st];
        __syncthreads();
    }
    float inv = 1.f / red[0];
    __syncthreads();
    if (t < 128) eo[t] *= inv;
    __syncthreads();
    // manip conv values
    if (t < 192) {
        int cls = t >> 6, o = t & 63;
        float a = mcb[o];
        const float* wp = Wc + (size_t)cls * 128 * 64 + o;
        for (int i = 0; i < 128; ++i) a = fmaf(eo[i], wp[(size_t)i * 64], a);
        m3[cls][o] = fmaxf(a, 0.f);
    }
    __syncthreads();
    // manip linear + token quantization (t = j 0..255)
    float a = mlb[t];
    for (int o = 0; o < MO; ++o) {
        a = fmaf(m3[0][o], mlw[((size_t)(o * H2 + 0)) * MJ + t], a);
        a = fmaf(m3[1][o], Lint[(size_t)o * MJ + t], a);
        a = fmaf(m3[2][o], mlw[((size_t)(o * H2 + 127)) * MJ + t], a);
    }
    tokens[(size_t)b * LL + t] = ((int)floorf(fabsf(a) * 100.f)) % NV;
}

// ---------- fuse F: reduce + head linear + softmax(14) ----------
__global__ __launch_bounds__(256) void k_fuseF(
        const float* __restrict__ partial, const float* __restrict__ flb1,
        const float* __restrict__ fl2, const float* __restrict__ fb2,
        float* __restrict__ outp) {
    int b = blockIdx.x, t = threadIdx.x;
    __shared__ float S[2][128];
    __shared__ float f1[128];
    __shared__ float sl[NV];
    int j = t & 127, hh = t >> 7;
    float s = 0.f;
    const float* pbase = partial + (size_t)b * H2 * JD + j;
    for (int h = hh * 64; h < hh * 64 + 64; ++h)
        s += pbase[(size_t)h * JD];
    S[hh][j] = s;
    __syncthreads();
    if (t < 128) f1[t] = S[0][t] + S[1][t] + flb1[t];
    __syncthreads();
    if (t < NV) {
        float a = fb2[t];
        for (int jj = 0; jj < 128; ++jj) a = fmaf(f1[jj], fl2[(size_t)jj * NV + t], a);
        sl[t] = a;
    }
    __syncthreads();
    if (t < NV) {
        float mx = -1e30f;
        for (int u = 0; u < NV; ++u) mx = fmaxf(mx, sl[u]);
        float ss = 0.f;
        for (int u = 0; u < NV; ++u) ss += expf(sl[u] - mx);
        outp[(size_t)b * NV + t] = expf(sl[t] - mx) / ss;
    }
}

extern "C" void kernel_launch(void* const* d_in, const int* in_sizes, int n_in,
                              void* d_out, int out_size, void* d_ws, size_t ws_size,
                              hipStream_t stream) {
    const int*   x    = (const int*)d_in[0];
    const float* eemb = (const float*)d_in[1];
    const float* ecw  = (const float*)d_in[2];
    const float* ecb  = (const float*)d_in[3];
    const float* elw  = (const float*)d_in[4];
    const float* elb  = (const float*)d_in[5];
    // d_in[6] rand_proj: provably unused (fog_of_war returns identity permutation)
    const float* mcw  = (const float*)d_in[7];
    const float* mcb  = (const float*)d_in[8];
    const float* mlw  = (const float*)d_in[9];
    const float* mlb  = (const float*)d_in[10];
    const float* femb = (const float*)d_in[11];
    const float* fcw  = (const float*)d_in[12];
    const float* fcb  = (const float*)d_in[13];
    const float* flw1 = (const float*)d_in[14];
    const float* flb1 = (const float*)d_in[15];
    const float* fl2  = (const float*)d_in[16];
    const float* fb2  = (const float*)d_in[17];
    float* outp = (float*)d_out;

    char* w = (char*)d_ws;
    size_t off = 0;
    auto alloc = [&](size_t bytes) {
        void* p = w + off;
        off = (off + bytes + 255) & ~(size_t)255;
        return p;
    };
    float* P      = (float*)alloc(2ull * NP * EMBD * 4);        // 0.8 MB
    float* cwT    = (float*)alloc(2ull * 3 * EMBD * OC * 4);    // 3.1 MB
    float* C      = (float*)alloc(2ull * NP * 3 * OC * 4);      // 1.2 MB
    float* Wc     = (float*)alloc(3ull * 128 * 64 * 4);
    float* Lint   = (float*)alloc(64ull * MJ * 4);
    int*   tokens = (int*)alloc((size_t)BB * LL * 4);
    float* partial= (float*)alloc((size_t)BB * H2 * JD * 4);    // 16.8 MB, [b][h][j]
    unsigned short* lwT_hi = (unsigned short*)alloc(2ull * H2 * 128 * 256 * 2); // 16.8 MB
    unsigned short* lwT_lo = (unsigned short*)alloc(1ull * H2 * 128 * 256 * 2); // 8.4 MB

    const float* C_e = C;
    const float* C_f = C + (size_t)NP * 3 * OC;

    // ---- prep (pairs | cwt | manipw | lint | lwT transpose) ----
    k_prep<<<PB_PAIRS + PB_CWT + PB_MANIPW + PB_LINT + PB_LWT, 256, 0, stream>>>(
        eemb, femb, ecw, fcw, mcw, mlw, elw, flw1, P, cwT, Wc, Lint, lwT_hi, lwT_lo);
    // ---- pair contributions (full K, q-batch 4, cb folded) ----
    k_contrib<<<2 * 3 * 49, 256, 0, stream>>>(P, cwT, ecb, fcb, C);

    // ---- enemy branch (bf16x3 MFMA — token path needs near-fp32) ----
    k_gemm<1><<<dim3(H2, 4), 512, 0, stream>>>(x, C_e, lwT_hi, lwT_lo, partial);
    k_fuseE<<<BB, 256, 0, stream>>>(partial, elb, Wc, mcb, mlw, Lint, mlb, tokens);

    // ---- friend branch (plain bf16 MFMA) ----
    k_gemm<0><<<dim3(H2, 4), 512, 0, stream>>>(tokens, C_f,
        lwT_hi + (size_t)H2 * 128 * 256, nullptr, partial);
    k_fuseF<<<BB, 256, 0, stream>>>(partial, flb1, fl2, fb2, outp);
}

// Round 9
// 92.721 us; speedup vs baseline: 1.0899x; 1.0899x over previous
//
#include <hip/hip_runtime.h>
#include <hip/hip_bf16.h>
#include <math.h>

#define BB    256   // batch
#define LL    256   // seq len
#define NV    14    // vocab
#define EMBD  512
#define H2    128   // L//2
#define OC    256   // branch conv out channels
#define NP    196   // 14*14 ordered token pairs
#define JD    128   // branch linear out
#define MO    64    // manip conv out channels
#define MJ    256   // manip linear out

// prep block ranges
#define PB_CWT    256                   // 2 br * 4 o-chunks * 32 i-chunks
#define PB_MANIPW 96
#define PB_LINT   64

using s16x8 = __attribute__((ext_vector_type(8))) short;
using f32x4 = __attribute__((ext_vector_type(4))) float;

static __device__ __forceinline__ unsigned short f2bf_rne(float f) {
    unsigned int u = __float_as_uint(f);
    unsigned int r = (u + 0x7FFFu + ((u >> 16) & 1u)) >> 16;
    return (unsigned short)r;
}
static __device__ __forceinline__ float bf2f(unsigned short h) {
    return __uint_as_float(((unsigned int)h) << 16);
}

// ---------- combined prep: cwt (LDS transpose) | manipw | lint ----------
__global__ void k_prep(const float* __restrict__ cw_e, const float* __restrict__ cw_f,
                       const float* __restrict__ mcw, const float* __restrict__ mlw,
                       float* __restrict__ cwT, float* __restrict__ Wc,
                       float* __restrict__ Lint) {
    __shared__ float T[48][66];   // cwt transpose tile
    int bid = blockIdx.x;
    int t = threadIdx.x;
    if (bid < PB_CWT) {                    // cwt: coalesced read + LDS transpose
        int cb = bid;                      // 0..255
        int ic = cb & 31;                  // i-chunk (16 i's)
        int oc = (cb >> 5) & 3;            // o-chunk (64 o's)
        int br = cb >> 7;                  // branch
        int i0 = ic * 16, o0 = oc * 64;
        const float* cw = br ? cw_f : cw_e;
        int ol = t >> 2, part = t & 3;     // o_local 0..63, i-quarter 0..3
        const float* src = cw + ((size_t)(o0 + ol) * EMBD + i0) * 9 + part * 36;
        #pragma unroll
        for (int ii = 0; ii < 4; ++ii)
            #pragma unroll
            for (int kh = 0; kh < 3; ++kh)
                T[kh * 16 + part * 4 + ii][ol] = src[ii * 9 + kh * 3 + 1];
        __syncthreads();
        int lane = t & 63, r0 = t >> 6;
        for (int rr = r0; rr < 48; rr += 4) {
            int kh = rr >> 4, il = rr & 15;
            cwT[(((size_t)(br * 3 + kh)) * EMBD + i0 + il) * OC + o0 + lane] = T[rr][lane];
        }
    } else if (bid < PB_CWT + PB_MANIPW) { // manipw
        int idx = (bid - PB_CWT) * 256 + t;
        int o = idx & 63;
        int i = (idx >> 6) & 127;
        int cls = idx >> 13;
        const float* base = mcw + ((size_t)(o * 128 + i) * 3) * 3 + 1;
        float v = 0.f;
        if (cls != 2) { v += base[3]; v += base[6]; }
        else          { v += base[0]; v += base[3]; }
        if (cls == 1)   v += base[0];
        Wc[idx] = v;
    } else {                                // lint (full interior sum)
        int o = bid - (PB_CWT + PB_MANIPW);   // 0..63
        float s = 0.f;
        for (int h = 1; h <= 126; h++)
            s += mlw[((size_t)(o * H2 + h)) * MJ + t];
        Lint[o * 256 + t] = s;
    }
}

// ---------- pair contributions, full K, q-batch 4, inline pair-max ----------
__global__ __launch_bounds__(256) void k_contrib(
        const float* __restrict__ emb_e, const float* __restrict__ emb_f,
        const float* __restrict__ cwT,
        const float* __restrict__ cb_e, const float* __restrict__ cb_f,
        float* __restrict__ C) {
    int bid = blockIdx.x;               // (br*3+kh)*49+qg
    int qg = bid % 49;
    int kh = (bid / 49) % 3;
    int br = bid / 147;
    int o = threadIdx.x;
    const float* emb = br ? emb_f : emb_e;

    __shared__ float Pl[4][512];
    for (int idx = o; idx < 4 * 512; idx += 256) {
        int row = idx >> 9, col = idx & 511;
        int q = qg * 4 + row;
        int t1 = q / NV, t2 = q % NV;
        Pl[row][col] = fmaxf(emb[t1 * EMBD + col], emb[t2 * EMBD + col]);
    }
    __syncthreads();

    const float* w = cwT + ((size_t)(br * 3 + kh) * EMBD) * OC + o;
    float acc[4] = {0.f, 0.f, 0.f, 0.f};
    #pragma unroll 8
    for (int i = 0; i < 512; i++) {
        float wv = w[(size_t)i * OC];
        #pragma unroll
        for (int qq = 0; qq < 4; qq++) acc[qq] = fmaf(wv, Pl[qq][i], acc[qq]);
    }
    float cbv = (kh == 1) ? (br ? cb_f[o] : cb_e[o]) : 0.f;
    #pragma unroll
    for (int qq = 0; qq < 4; qq++)
        C[(((size_t)br * NP + qg * 4 + qq) * 3 + kh) * OC + o] = acc[qq] + cbv;
}

// ---------- MFMA GEMM: partial[b][h][j] = sum_o Y[b,h,o]*lw[(o*H2+h)*JD+j] ----------
// M-tile 64, grid (H2, 4) = 512 blocks, 8 waves 2m x 4n. SK = K per LDS stage.
// X3=1: bf16 hi/lo 3-product split (near-fp32); X3=0: plain bf16.
template <int X3, int SK>
__global__ __launch_bounds__(512) void k_gemm(
        const int* __restrict__ tok, const float* __restrict__ C,
        const float* __restrict__ lw, float* __restrict__ partial) {
    __shared__ unsigned short Ah[2][64][SK + 4];
    __shared__ unsigned short Al[X3 ? 2 : 1][X3 ? 64 : 1][X3 ? SK + 4 : 1];
    __shared__ unsigned short Bh[2][128][SK + 4];
    __shared__ unsigned short Bl[X3 ? 2 : 1][X3 ? 128 : 1][X3 ? SK + 4 : 1];

    const int h  = blockIdx.x;
    const int B0 = blockIdx.y * 64;
    const int t  = threadIdx.x;
    constexpr int NST = 256 / SK;       // stages
    constexpr int KQ  = SK / 8;         // A floats per thread (per C-row)
    constexpr int JW  = SK / 4;         // B floats per thread

    // ---- A gather setup (thread: row am 0..63, k-chunk kq of KQ floats)
    const int am = t >> 3;
    const int kq = (t & 7) * KQ;
    const int* tb = tok + (size_t)(B0 + am) * LL;
    const int q1 = tb[2 * h] * NV + tb[2 * h + 1];
    const float* r1 = C + ((size_t)q1 * 3 + 1) * OC + kq;
    const float* r0 = nullptr;
    const float* r2 = nullptr;
    if (h > 0)      { int q0 = tb[2 * h - 2] * NV + tb[2 * h - 1]; r0 = C + ((size_t)q0 * 3 + 0) * OC + kq; }
    if (h < H2 - 1) { int q2 = tb[2 * h + 2] * NV + tb[2 * h + 3]; r2 = C + ((size_t)q2 * 3 + 2) * OC + kq; }

    // ---- B setup (thread: k-row ko 0..SK-1, JW j's at j0)
    const int ko = t & (SK - 1);
    const int j0 = (t / SK) * JW;
    const float* wsrc = lw + ((size_t)ko * H2 + h) * JD + j0;

    float4 ya[SK / 32], yb[SK / 32], yc[SK / 32], wv4[SK / 16];

    auto load = [&](int s) {
        #pragma unroll
        for (int p = 0; p < SK / 32; ++p) {
            ya[p] = *(const float4*)(r1 + s * SK + 4 * p);
            if (r0) yb[p] = *(const float4*)(r0 + s * SK + 4 * p);
            else    yb[p] = make_float4(0, 0, 0, 0);
            if (r2) yc[p] = *(const float4*)(r2 + s * SK + 4 * p);
            else    yc[p] = make_float4(0, 0, 0, 0);
        }
        const float* pw = wsrc + (size_t)s * SK * H2 * JD;
        #pragma unroll
        for (int p = 0; p < SK / 16; ++p)
            wv4[p] = *(const float4*)(pw + 4 * p);
    };

    auto store = [&](int buf) {
        #pragma unroll
        for (int p = 0; p < SK / 32; ++p) {
            float y[4];
            y[0] = ya[p].x + yb[p].x + yc[p].x; y[1] = ya[p].y + yb[p].y + yc[p].y;
            y[2] = ya[p].z + yb[p].z + yc[p].z; y[3] = ya[p].w + yb[p].w + yc[p].w;
            unsigned short hi[4];
            #pragma unroll
            for (int e = 0; e < 4; ++e) hi[e] = f2bf_rne(y[e]);
            uint2 u;
            u.x = (unsigned)hi[0] | ((unsigned)hi[1] << 16);
            u.y = (unsigned)hi[2] | ((unsigned)hi[3] << 16);
            *(uint2*)&Ah[buf][am][kq + 4 * p] = u;
            if (X3) {
                unsigned short lo[4];
                #pragma unroll
                for (int e = 0; e < 4; ++e) lo[e] = f2bf_rne(y[e] - bf2f(hi[e]));
                uint2 v;
                v.x = (unsigned)lo[0] | ((unsigned)lo[1] << 16);
                v.y = (unsigned)lo[2] | ((unsigned)lo[3] << 16);
                *(uint2*)&Al[buf][am][kq + 4 * p] = v;
            }
        }
        #pragma unroll
        for (int p = 0; p < SK / 16; ++p) {
            float wf[4] = {wv4[p].x, wv4[p].y, wv4[p].z, wv4[p].w};
            #pragma unroll
            for (int e = 0; e < 4; ++e) {
                unsigned short wh = f2bf_rne(wf[e]);
                Bh[buf][j0 + p * 4 + e][ko] = wh;
                if (X3) Bl[buf][j0 + p * 4 + e][ko] = f2bf_rne(wf[e] - bf2f(wh));
            }
        }
    };

    // ---- compute mapping: 8 waves = 2m x 4n; wave tile 32m x 32n
    const int lane = t & 63, wid = t >> 6;
    const int Wm = (wid >> 2) * 32;     // 0 or 32
    const int Wn = (wid & 3) * 32;      // 0,32,64,96
    const int fr = lane & 15;
    const int g8 = (lane >> 4) * 8;

    f32x4 acc[2][2] = {};

    auto rd8 = [&](const unsigned short* p) -> s16x8 {
        union { s16x8 v; uint2 u[2]; } tmp;
        tmp.u[0] = *(const uint2*)(p);
        tmp.u[1] = *(const uint2*)(p + 4);
        return tmp.v;
    };

    auto compute = [&](int buf) {
        #pragma unroll
        for (int kk0 = 0; kk0 < SK; kk0 += 32) {
            s16x8 a_h[2], b_h[2];
            #pragma unroll
            for (int mf = 0; mf < 2; ++mf) a_h[mf] = rd8(&Ah[buf][Wm + mf * 16 + fr][kk0 + g8]);
            #pragma unroll
            for (int nf = 0; nf < 2; ++nf) b_h[nf] = rd8(&Bh[buf][Wn + nf * 16 + fr][kk0 + g8]);
            #pragma unroll
            for (int mf = 0; mf < 2; ++mf)
                #pragma unroll
                for (int nf = 0; nf < 2; ++nf)
                    acc[mf][nf] = __builtin_amdgcn_mfma_f32_16x16x32_bf16(a_h[mf], b_h[nf], acc[mf][nf], 0, 0, 0);
            if (X3) {
                s16x8 a_l[2], b_l[2];
                #pragma unroll
                for (int mf = 0; mf < 2; ++mf) a_l[mf] = rd8(&Al[buf][Wm + mf * 16 + fr][kk0 + g8]);
                #pragma unroll
                for (int nf = 0; nf < 2; ++nf) b_l[nf] = rd8(&Bl[buf][Wn + nf * 16 + fr][kk0 + g8]);
                #pragma unroll
                for (int mf = 0; mf < 2; ++mf)
                    #pragma unroll
                    for (int nf = 0; nf < 2; ++nf) {
                        acc[mf][nf] = __builtin_amdgcn_mfma_f32_16x16x32_bf16(a_h[mf], b_l[nf], acc[mf][nf], 0, 0, 0);
                        acc[mf][nf] = __builtin_amdgcn_mfma_f32_16x16x32_bf16(a_l[mf], b_h[nf], acc[mf][nf], 0, 0, 0);
                    }
            }
        }
    };

    // ---- main loop
    load(0);
    store(0);
    __syncthreads();
    for (int s = 0; s < NST; ++s) {
        if (s < NST - 1) load(s + 1);
        compute(s & 1);
        if (s < NST - 1) store((s + 1) & 1);
        __syncthreads();
    }

    // ---- epilogue: partial[b][h][j]; D mapping col=lane&15, row=4*(lane>>4)+reg
    float* pb = partial + (((size_t)(B0 + Wm)) * H2 + h) * JD + Wn;
    #pragma unroll
    for (int mf = 0; mf < 2; ++mf)
        #pragma unroll
        for (int nf = 0; nf < 2; ++nf)
            #pragma unroll
            for (int r = 0; r < 4; ++r) {
                int row = mf * 16 + (lane >> 4) * 4 + r;
                int col = nf * 16 + fr;
                pb[(size_t)row * H2 * JD + col] = acc[mf][nf][r];
            }
}

// ---------- fuse E: reduce + softmax + manip conv + manip linear + tokens ----------
__global__ __launch_bounds__(256) void k_fuseE(
        const float* __restrict__ partial, const float* __restrict__ elb,
        const float* __restrict__ Wc, const float* __restrict__ mcb,
        const float* __restrict__ mlw, const float* __restrict__ Lint,
        const float* __restrict__ mlb, int* __restrict__ tokens) {
    int b = blockIdx.x, t = threadIdx.x;
    __shared__ float S[2][128];
    __shared__ float eo[128];
    __shared__ float m3[3][64];
    __shared__ float red[128];

    int j = t & 127, hh = t >> 7;
    float s = 0.f;
    const float* pbase = partial + (size_t)b * H2 * JD + j;
    for (int h = hh * 64; h < hh * 64 + 64; ++h)
        s += pbase[(size_t)h * JD];
    S[hh][j] = s;
    __syncthreads();
    if (t < 128) {
        float v = S[0][t] + S[1][t] + elb[t];
        S[0][t] = v;
        red[t] = v;
    }
    __syncthreads();
    for (int st = 64; st > 0; st >>= 1) {
        if (t < st) red[t] = fmaxf(red[t], red[t + st]);
        __syncthreads();
    }
    float mx = red[0];
    __syncthreads();
    if (t < 128) {
        float e = expf(S[0][t] - mx);
        eo[t] = e;
        red[t] = e;
    }
    __syncthreads();
    for (int st = 64; st > 0; st >>= 1) {
        if (t < st) red[t] += red[t + st];
        __syncthreads();
    }
    float inv = 1.f / red[0];
    __syncthreads();
    if (t < 128) eo[t] *= inv;
    __syncthreads();
    // manip conv values
    if (t < 192) {
        int cls = t >> 6, o = t & 63;
        float a = mcb[o];
        const float* wp = Wc + (size_t)cls * 128 * 64 + o;
        for (int i = 0; i < 128; ++i) a = fmaf(eo[i], wp[(size_t)i * 64], a);
        m3[cls][o] = fmaxf(a, 0.f);
    }
    __syncthreads();
    // manip linear + token quantization (t = j 0..255)
    float a = mlb[t];
    for (int o = 0; o < MO; ++o) {
        a = fmaf(m3[0][o], mlw[((size_t)(o * H2 + 0)) * MJ + t], a);
        a = fmaf(m3[1][o], Lint[(size_t)o * MJ + t], a);
        a = fmaf(m3[2][o], mlw[((size_t)(o * H2 + 127)) * MJ + t], a);
    }
    tokens[(size_t)b * LL + t] = ((int)floorf(fabsf(a) * 100.f)) % NV;
}

// ---------- fuse F: reduce + head linear + softmax(14) ----------
__global__ __launch_bounds__(256) void k_fuseF(
        const float* __restrict__ partial, const float* __restrict__ flb1,
        const float* __restrict__ fl2, const float* __restrict__ fb2,
        float* __restrict__ outp) {
    int b = blockIdx.x, t = threadIdx.x;
    __shared__ float S[2][128];
    __shared__ float f1[128];
    __shared__ float sl[NV];
    int j = t & 127, hh = t >> 7;
    float s = 0.f;
    const float* pbase = partial + (size_t)b * H2 * JD + j;
    for (int h = hh * 64; h < hh * 64 + 64; ++h)
        s += pbase[(size_t)h * JD];
    S[hh][j] = s;
    __syncthreads();
    if (t < 128) f1[t] = S[0][t] + S[1][t] + flb1[t];
    __syncthreads();
    if (t < NV) {
        float a = fb2[t];
        for (int jj = 0; jj < 128; ++jj) a = fmaf(f1[jj], fl2[(size_t)jj * NV + t], a);
        sl[t] = a;
    }
    __syncthreads();
    if (t < NV) {
        float mx = -1e30f;
        for (int u = 0; u < NV; ++u) mx = fmaxf(mx, sl[u]);
        float ss = 0.f;
        for (int u = 0; u < NV; ++u) ss += expf(sl[u] - mx);
        outp[(size_t)b * NV + t] = expf(sl[t] - mx) / ss;
    }
}

extern "C" void kernel_launch(void* const* d_in, const int* in_sizes, int n_in,
                              void* d_out, int out_size, void* d_ws, size_t ws_size,
                              hipStream_t stream) {
    const int*   x    = (const int*)d_in[0];
    const float* eemb = (const float*)d_in[1];
    const float* ecw  = (const float*)d_in[2];
    const float* ecb  = (const float*)d_in[3];
    const float* elw  = (const float*)d_in[4];
    const float* elb  = (const float*)d_in[5];
    // d_in[6] rand_proj: provably unused (fog_of_war returns identity permutation)
    const float* mcw  = (const float*)d_in[7];
    const float* mcb  = (const float*)d_in[8];
    const float* mlw  = (const float*)d_in[9];
    const float* mlb  = (const float*)d_in[10];
    const float* femb = (const float*)d_in[11];
    const float* fcw  = (const float*)d_in[12];
    const float* fcb  = (const float*)d_in[13];
    const float* flw1 = (const float*)d_in[14];
    const float* flb1 = (const float*)d_in[15];
    const float* fl2  = (const float*)d_in[16];
    const float* fb2  = (const float*)d_in[17];
    float* outp = (float*)d_out;

    char* w = (char*)d_ws;
    size_t off = 0;
    auto alloc = [&](size_t bytes) {
        void* p = w + off;
        off = (off + bytes + 255) & ~(size_t)255;
        return p;
    };
    float* cwT    = (float*)alloc(2ull * 3 * EMBD * OC * 4);    // 3.1 MB
    float* C      = (float*)alloc(2ull * NP * 3 * OC * 4);      // 1.2 MB
    float* Wc     = (float*)alloc(3ull * 128 * 64 * 4);
    float* Lint   = (float*)alloc(64ull * MJ * 4);
    int*   tokens = (int*)alloc((size_t)BB * LL * 4);
    float* partial= (float*)alloc((size_t)BB * H2 * JD * 4);    // 16.8 MB, [b][h][j]

    const float* C_e = C;
    const float* C_f = C + (size_t)NP * 3 * OC;

    // ---- prep (cwt | manipw | lint) ----
    k_prep<<<PB_CWT + PB_MANIPW + PB_LINT, 256, 0, stream>>>(
        ecw, fcw, mcw, mlw, cwT, Wc, Lint);
    // ---- pair contributions (full K, q-batch 4, inline pair-max, cb folded) ----
    k_contrib<<<2 * 3 * 49, 256, 0, stream>>>(eemb, femb, cwT, ecb, fcb, C);

    // ---- enemy branch (bf16x3 MFMA — token path needs near-fp32) ----
    k_gemm<1, 32><<<dim3(H2, 4), 512, 0, stream>>>(x, C_e, elw, partial);
    k_fuseE<<<BB, 256, 0, stream>>>(partial, elb, Wc, mcb, mlw, Lint, mlb, tokens);

    // ---- friend branch (plain bf16 MFMA, K-stage 64: half the barriers) ----
    k_gemm<0, 64><<<dim3(H2, 4), 512, 0, stream>>>(tokens, C_f, flw1, partial);
    k_fuseF<<<BB, 256, 0, stream>>>(partial, flb1, fl2, fb2, outp);
}